// Round 3
// baseline (1646.342 us; speedup 1.0000x reference)
//
#include <hip/hip_runtime.h>
#include <hip/hip_bf16.h>
#include <stdint.h>

#define S_LEN 2048
#define NH    16
#define HD    128
#define HDIM  2048
#define H3    6144

typedef unsigned short u16;
typedef __attribute__((ext_vector_type(8))) short short8;
typedef __attribute__((ext_vector_type(4))) float floatx4;

__device__ __forceinline__ u16 f2bf(float f) {
  union { float f; uint32_t u; } v; v.f = f;
  uint32_t r = v.u + 0x7fffu + ((v.u >> 16) & 1u);
  return (u16)(r >> 16);
}
__device__ __forceinline__ float bf2f(u16 u) {
  union { uint32_t u; float f; } v; v.u = ((uint32_t)u) << 16;
  return v.f;
}

__device__ __forceinline__ void async16(const void* g, void* l) {
  __builtin_amdgcn_global_load_lds((const __attribute__((address_space(1))) void*)g,
                                   (__attribute__((address_space(3))) void*)l, 16, 0, 0);
}

// ---------------- fp32 -> bf16 convert ----------------
__global__ void cvt_bf16(const float* __restrict__ src, u16* __restrict__ dst, int n4) {
  int i = blockIdx.x * 256 + threadIdx.x;
  if (i < n4) {
    float4 v = ((const float4*)src)[i];
    ushort4 o;
    o.x = f2bf(v.x); o.y = f2bf(v.y); o.z = f2bf(v.z); o.w = f2bf(v.w);
    ((ushort4*)dst)[i] = o;
  }
}

// ---------------- RoPE cos/sin table: cs[s*64+i] = {cos,sin} ----------------
__global__ void rope_table(float2* __restrict__ cs) {
  int gid = blockIdx.x * 256 + threadIdx.x;      // 131072 = 2048*64
  int s = gid >> 6, i = gid & 63;
  float f = (float)s * exp2f(-(float)i * 0.20762050593046337f);
  float sn, c;
  sincosf(f, &sn, &c);
  cs[gid] = make_float2(c, sn);
}

// ---------------- GEMM: C = A @ B^T  (A: MxK bf16, B: NxK bf16) ----------------
template <int OUT_F32>
__global__ void gemm_bt(const u16* __restrict__ A, const u16* __restrict__ B,
                        void* __restrict__ Cv, int M, int N, int K) {
  __shared__ __align__(16) u16 As[128 * 32];
  __shared__ __align__(16) u16 Bs[128 * 32];
  const int t = threadIdx.x;
  const int w = t >> 6, lane = t & 63;
  const int wr = w >> 1, wc = w & 1;
  const int row0 = blockIdx.y * 128, col0 = blockIdx.x * 128;
  const int lr = lane & 15, lk = lane >> 4;
  const int srow = lane >> 2, scol = (lane & 3) * 8;

  floatx4 acc[4][4];
#pragma unroll
  for (int i = 0; i < 4; ++i)
#pragma unroll
    for (int j = 0; j < 4; ++j) acc[i][j] = (floatx4){0.f, 0.f, 0.f, 0.f};

  for (int k0 = 0; k0 < K; k0 += 32) {
    __syncthreads();
#pragma unroll
    for (int ss = 0; ss < 2; ++ss) {
      int s = w + ss * 4;
      const u16* gA = A + (size_t)(row0 + s * 16 + srow) * K + k0 + scol;
      const u16* gB = B + (size_t)(col0 + s * 16 + srow) * K + k0 + scol;
      async16(gA, (char*)As + s * 1024);
      async16(gB, (char*)Bs + s * 1024);
    }
    __syncthreads();
    short8 a[4], b[4];
#pragma unroll
    for (int mi = 0; mi < 4; ++mi)
      a[mi] = *(const short8*)((const char*)As + (wr * 64 + mi * 16 + lr) * 64 + lk * 16);
#pragma unroll
    for (int ni = 0; ni < 4; ++ni)
      b[ni] = *(const short8*)((const char*)Bs + (wc * 64 + ni * 16 + lr) * 64 + lk * 16);
#pragma unroll
    for (int mi = 0; mi < 4; ++mi)
#pragma unroll
      for (int ni = 0; ni < 4; ++ni)
        acc[mi][ni] = __builtin_amdgcn_mfma_f32_16x16x32_bf16(a[mi], b[ni], acc[mi][ni], 0, 0, 0);
  }

#pragma unroll
  for (int mi = 0; mi < 4; ++mi)
#pragma unroll
    for (int ni = 0; ni < 4; ++ni)
#pragma unroll
      for (int r = 0; r < 4; ++r) {
        int row = row0 + wr * 64 + mi * 16 + lk * 4 + r;
        int col = col0 + wc * 64 + ni * 16 + lr;
        float v = acc[mi][ni][r];
        if (OUT_F32) ((float*)Cv)[(size_t)row * N + col] = v;
        else         ((u16*)Cv)[(size_t)row * N + col] = f2bf(v);
      }
}

// ---------------- RoPE q,k + relayout to (bh, S, 128) ----------------
__global__ void rope_qk(const u16* __restrict__ qkvb, const float2* __restrict__ cs,
                        u16* __restrict__ Qt, u16* __restrict__ Kt) {
  const int t = threadIdx.x;
  const int bh = blockIdx.y, s0 = blockIdx.x * 64;
  const int b = bh >> 4, h = bh & 15;
  const int rg = t >> 4;             // 0..15 row-in-group
  const int i4 = (t & 15) * 4;       // 0..60
#pragma unroll
  for (int pass = 0; pass < 4; ++pass) {
    const int s = s0 + pass * 16 + rg;
    float c[4], sn[4];
#pragma unroll
    for (int z = 0; z < 4; ++z) { float2 v = cs[s * 64 + i4 + z]; c[z] = v.x; sn[z] = v.y; }
#pragma unroll
    for (int m = 0; m < 2; ++m) {
      const u16* src = qkvb + (size_t)(b * S_LEN + s) * H3 + m * HDIM + h * HD;
      ushort4 x1 = *(const ushort4*)(src + i4);
      ushort4 x2 = *(const ushort4*)(src + i4 + 64);
      float a1[4] = {bf2f(x1.x), bf2f(x1.y), bf2f(x1.z), bf2f(x1.w)};
      float a2[4] = {bf2f(x2.x), bf2f(x2.y), bf2f(x2.z), bf2f(x2.w)};
      ushort4 o1, o2;
      o1.x = f2bf(a1[0] * c[0] - a2[0] * sn[0]);  o2.x = f2bf(a2[0] * c[0] + a1[0] * sn[0]);
      o1.y = f2bf(a1[1] * c[1] - a2[1] * sn[1]);  o2.y = f2bf(a2[1] * c[1] + a1[1] * sn[1]);
      o1.z = f2bf(a1[2] * c[2] - a2[2] * sn[2]);  o2.z = f2bf(a2[2] * c[2] + a1[2] * sn[2]);
      o1.w = f2bf(a1[3] * c[3] - a2[3] * sn[3]);  o2.w = f2bf(a2[3] * c[3] + a1[3] * sn[3]);
      u16* dst = (m ? Kt : Qt) + (size_t)(bh * S_LEN + s) * HD;
      *(ushort4*)(dst + i4) = o1;
      *(ushort4*)(dst + i4 + 64) = o2;
    }
  }
}

// ---------------- V transpose to (bh, 128, S) ----------------
__global__ void v_trans(const u16* __restrict__ qkvb, u16* __restrict__ Vt) {
  __shared__ u16 tile[64][132];
  const int t = threadIdx.x;
  const int bh = blockIdx.y, s0 = blockIdx.x * 64;
  const int b = bh >> 4, h = bh & 15;
#pragma unroll
  for (int it = 0; it < 8; ++it) {
    int u = it * 256 + t;
    int row = u >> 5;                 // 0..63 (s)
    int d4 = (u & 31) * 4;            // 0..124
    ushort4 vv = *(const ushort4*)(qkvb + (size_t)(b * S_LEN + s0 + row) * H3 + 2 * HDIM + h * HD + d4);
    tile[row][d4 + 0] = vv.x; tile[row][d4 + 1] = vv.y;
    tile[row][d4 + 2] = vv.z; tile[row][d4 + 3] = vv.w;
  }
  __syncthreads();
#pragma unroll
  for (int it = 0; it < 8; ++it) {
    int u = it * 256 + t;
    int d = u >> 4;                   // 0..127
    int s4 = (u & 15) * 4;            // 0..60
    ushort4 ov;
    ov.x = tile[s4 + 0][d]; ov.y = tile[s4 + 1][d];
    ov.z = tile[s4 + 2][d]; ov.w = tile[s4 + 3][d];
    *(ushort4*)(Vt + (size_t)(bh * HD + d) * S_LEN + s0 + s4) = ov;
  }
}

// ---------------- causal flash attention, balanced pairing ----------------
// grid (16, 32), 4 waves. Wave w of block x owns 16-row q-tiles t=4x+w and
// 127-t  -> every wave runs exactly 65 KV iterations (perfect balance).
// K(kt+1) register-prefetch + early V loads hide L2 latency; no asm fences.
__global__ void attn_fwd(const u16* __restrict__ Qt, const u16* __restrict__ Kt,
                         const u16* __restrict__ Vt, u16* __restrict__ Ao) {
  __shared__ __align__(16) u16 Pl[4][512];     // per-wave 16x32 P tile
  const int t = threadIdx.x, w = t >> 6, lane = t & 63;
  const int lr = lane & 15, lk = lane >> 4;
  const int bh = blockIdx.y;
  const int b = bh >> 4, h = bh & 15;
  const u16* Qb = Qt + (size_t)bh * S_LEN * HD;
  const u16* Kb = Kt + (size_t)bh * S_LEN * HD;
  const u16* Vb = Vt + (size_t)bh * HD * S_LEN;
  u16* Pw = &Pl[w][0];
  const float scale = 0.08838834764831845f;    // 1/sqrt(128)
  const int tbase = blockIdx.x * 4 + w;        // 0..63

#pragma unroll 1
  for (int half = 0; half < 2; ++half) {
    const int qt = half ? (127 - tbase) : tbase;
    const int qw0 = qt * 16;

    short8 aq[4];
#pragma unroll
    for (int c = 0; c < 4; ++c)
      aq[c] = *(const short8*)(Qb + (size_t)(qw0 + lr) * HD + c * 32 + lk * 8);

    floatx4 o[8];
#pragma unroll
    for (int i = 0; i < 8; ++i) o[i] = (floatx4){0.f, 0.f, 0.f, 0.f};
    float mrow[4] = {-1e30f, -1e30f, -1e30f, -1e30f};
    float lrow[4] = {0.f, 0.f, 0.f, 0.f};

    const int nkt = (qw0 + 47) >> 5;           // ceil((qw0+16)/32)

    short8 kc0[4], kc1[4];
#pragma unroll
    for (int c = 0; c < 4; ++c) {
      kc0[c] = *(const short8*)(Kb + (size_t)lr * HD + c * 32 + lk * 8);
      kc1[c] = *(const short8*)(Kb + (size_t)(16 + lr) * HD + c * 32 + lk * 8);
    }

    for (int kt = 0; kt < nkt; ++kt) {
      const int kv0 = kt * 32;
      const bool more = (kt + 1) < nkt;

      // prefetch next K tile into registers (latency hidden under this iter)
      short8 kn0[4], kn1[4];
      if (more) {
#pragma unroll
        for (int c = 0; c < 4; ++c) {
          kn0[c] = *(const short8*)(Kb + (size_t)(kv0 + 32 + lr) * HD + c * 32 + lk * 8);
          kn1[c] = *(const short8*)(Kb + (size_t)(kv0 + 48 + lr) * HD + c * 32 + lk * 8);
        }
      }
      // V loads issued before QK compute (hidden under QK+softmax)
      short8 vv[8];
#pragma unroll
      for (int ni = 0; ni < 8; ++ni)
        vv[ni] = *(const short8*)(Vb + (size_t)(ni * 16 + lr) * S_LEN + kv0 + lk * 8);

      floatx4 s0 = (floatx4){0.f,0.f,0.f,0.f}, s1 = (floatx4){0.f,0.f,0.f,0.f};
      __builtin_amdgcn_s_setprio(1);
#pragma unroll
      for (int c = 0; c < 4; ++c) {
        s0 = __builtin_amdgcn_mfma_f32_16x16x32_bf16(aq[c], kc0[c], s0, 0, 0, 0);
        s1 = __builtin_amdgcn_mfma_f32_16x16x32_bf16(aq[c], kc1[c], s1, 0, 0, 0);
      }
      __builtin_amdgcn_s_setprio(0);

      const bool need_mask = (kv0 + 31) > qw0;
      float p0[4], p1[4], tmx[4];
#pragma unroll
      for (int r = 0; r < 4; ++r) {
        float v0 = s0[r] * scale, v1 = s1[r] * scale;
        if (need_mask) {
          int row = qw0 + lk * 4 + r;
          if (kv0 + lr > row)      v0 = -1e30f;
          if (kv0 + 16 + lr > row) v1 = -1e30f;
        }
        float tm = fmaxf(v0, v1);
        tm = fmaxf(tm, __shfl_xor(tm, 1));
        tm = fmaxf(tm, __shfl_xor(tm, 2));
        tm = fmaxf(tm, __shfl_xor(tm, 4));
        tm = fmaxf(tm, __shfl_xor(tm, 8));
        tmx[r] = tm; p0[r] = v0; p1[r] = v1;
      }

      bool ok = (tmx[0] <= mrow[0] + 8.f) && (tmx[1] <= mrow[1] + 8.f) &&
                (tmx[2] <= mrow[2] + 8.f) && (tmx[3] <= mrow[3] + 8.f);
      if (__all(ok)) {
        // defer-max: no rescale needed (P bounded by e^8)
#pragma unroll
        for (int r = 0; r < 4; ++r) {
          float e0 = __expf(p0[r] - mrow[r]), e1 = __expf(p1[r] - mrow[r]);
          float sum = e0 + e1;
          sum += __shfl_xor(sum, 1); sum += __shfl_xor(sum, 2);
          sum += __shfl_xor(sum, 4); sum += __shfl_xor(sum, 8);
          lrow[r] += sum;
          p0[r] = e0; p1[r] = e1;
        }
      } else {
#pragma unroll
        for (int r = 0; r < 4; ++r) {
          float mnew = fmaxf(mrow[r], tmx[r]);
          float alpha = __expf(mrow[r] - mnew);
          mrow[r] = mnew;
          float e0 = __expf(p0[r] - mnew), e1 = __expf(p1[r] - mnew);
          float sum = e0 + e1;
          sum += __shfl_xor(sum, 1); sum += __shfl_xor(sum, 2);
          sum += __shfl_xor(sum, 4); sum += __shfl_xor(sum, 8);
          lrow[r] = lrow[r] * alpha + sum;
          p0[r] = e0; p1[r] = e1;
#pragma unroll
          for (int ni = 0; ni < 8; ++ni) o[ni][r] *= alpha;
        }
      }

      // P -> LDS transpose (wave-private; compiler inserts the lgkm wait)
#pragma unroll
      for (int r = 0; r < 4; ++r) {
        Pw[(lk * 4 + r) * 32 + lr]      = f2bf(p0[r]);
        Pw[(lk * 4 + r) * 32 + 16 + lr] = f2bf(p1[r]);
      }
      short8 pa = *(const short8*)((const char*)Pw + lr * 64 + lk * 16);

      __builtin_amdgcn_s_setprio(1);
#pragma unroll
      for (int ni = 0; ni < 8; ++ni)
        o[ni] = __builtin_amdgcn_mfma_f32_16x16x32_bf16(pa, vv[ni], o[ni], 0, 0, 0);
      __builtin_amdgcn_s_setprio(0);

      if (more) {
#pragma unroll
        for (int c = 0; c < 4; ++c) { kc0[c] = kn0[c]; kc1[c] = kn1[c]; }
      }
    }

    float inv[4];
#pragma unroll
    for (int r = 0; r < 4; ++r) inv[r] = 1.0f / lrow[r];
#pragma unroll
    for (int ni = 0; ni < 8; ++ni)
#pragma unroll
      for (int r = 0; r < 4; ++r) {
        int row = qw0 + lk * 4 + r;
        Ao[(size_t)(b * S_LEN + row) * HDIM + h * HD + ni * 16 + lr] = f2bf(o[ni][r] * inv[r]);
      }
  }
}

extern "C" void kernel_launch(void* const* d_in, const int* in_sizes, int n_in,
                              void* d_out, int out_size, void* d_ws, size_t ws_size,
                              hipStream_t stream) {
  const float* x    = (const float*)d_in[0];
  // d_in[1] = attn_mask: pure causal, reconstructed analytically — never read.
  const float* Wqkv = (const float*)d_in[2];
  const float* Wout = (const float*)d_in[3];
  float* out = (float*)d_out;
  char* ws = (char*)d_ws;

  u16* xb       = (u16*)(ws + 0);              // 16.8 MB  (aliased by attn_out later)
  u16* wqkvb    = (u16*)(ws + 16777216);       // 25.2 MB
  u16* woutb    = (u16*)(ws + 41943040);       //  8.4 MB
  u16* qkvb     = (u16*)(ws + 50331648);       // 50.3 MB
  u16* Qt       = (u16*)(ws + 100663296);      // 16.8 MB
  u16* Kt       = (u16*)(ws + 117440512);      // 16.8 MB
  u16* Vt       = (u16*)(ws + 134217728);      // 16.8 MB
  float2* cs    = (float2*)(ws + 150994944);   //  1.0 MB   total ~145 MB
  u16* attn_out = xb;                          // xb dead after GEMM1

  cvt_bf16<<<8192,  256, 0, stream>>>(x,    xb,    2097152);
  cvt_bf16<<<12288, 256, 0, stream>>>(Wqkv, wqkvb, 3145728);
  cvt_bf16<<<4096,  256, 0, stream>>>(Wout, woutb, 1048576);
  rope_table<<<512, 256, 0, stream>>>(cs);

  gemm_bt<0><<<dim3(48, 32), 256, 0, stream>>>(xb, wqkvb, qkvb, 4096, H3, HDIM);

  rope_qk<<<dim3(32, 32), 256, 0, stream>>>(qkvb, cs, Qt, Kt);
  v_trans<<<dim3(32, 32), 256, 0, stream>>>(qkvb, Vt);

  attn_fwd<<<dim3(16, 32), 256, 0, stream>>>(Qt, Kt, Vt, attn_out);

  gemm_bt<1><<<dim3(16, 32), 256, 0, stream>>>(attn_out, woutb, out, 4096, HDIM, HDIM);
}

// Round 4
// 571.998 us; speedup vs baseline: 2.8782x; 2.8782x over previous
//
#include <hip/hip_runtime.h>
#include <hip/hip_bf16.h>
#include <stdint.h>

#define S_LEN 2048
#define NH    16
#define HD    128
#define HDIM  2048
#define H3    6144

typedef unsigned short u16;
typedef __attribute__((ext_vector_type(8))) short short8;
typedef __attribute__((ext_vector_type(4))) float floatx4;

__device__ __forceinline__ u16 f2bf(float f) {
  union { float f; uint32_t u; } v; v.f = f;
  uint32_t r = v.u + 0x7fffu + ((v.u >> 16) & 1u);
  return (u16)(r >> 16);
}
__device__ __forceinline__ float bf2f(u16 u) {
  union { uint32_t u; float f; } v; v.u = ((uint32_t)u) << 16;
  return v.f;
}

__device__ __forceinline__ void async16(const void* g, void* l) {
  __builtin_amdgcn_global_load_lds((const __attribute__((address_space(1))) void*)g,
                                   (__attribute__((address_space(3))) void*)l, 16, 0, 0);
}

// ---------------- fp32 -> bf16 convert ----------------
__global__ void cvt_bf16(const float* __restrict__ src, u16* __restrict__ dst, int n4) {
  int i = blockIdx.x * 256 + threadIdx.x;
  if (i < n4) {
    float4 v = ((const float4*)src)[i];
    ushort4 o;
    o.x = f2bf(v.x); o.y = f2bf(v.y); o.z = f2bf(v.z); o.w = f2bf(v.w);
    ((ushort4*)dst)[i] = o;
  }
}

// ---------------- RoPE cos/sin table: cs[s*64+i] = {cos,sin} ----------------
__global__ void rope_table(float2* __restrict__ cs) {
  int gid = blockIdx.x * 256 + threadIdx.x;      // 131072 = 2048*64
  int s = gid >> 6, i = gid & 63;
  float f = (float)s * exp2f(-(float)i * 0.20762050593046337f);
  float sn, c;
  sincosf(f, &sn, &c);
  cs[gid] = make_float2(c, sn);
}

// ---------------- GEMM: C = A @ B^T  (A: MxK bf16, B: NxK bf16) ----------------
template <int OUT_F32>
__global__ void gemm_bt(const u16* __restrict__ A, const u16* __restrict__ B,
                        void* __restrict__ Cv, int M, int N, int K) {
  __shared__ __align__(16) u16 As[128 * 32];
  __shared__ __align__(16) u16 Bs[128 * 32];
  const int t = threadIdx.x;
  const int w = t >> 6, lane = t & 63;
  const int wr = w >> 1, wc = w & 1;
  const int row0 = blockIdx.y * 128, col0 = blockIdx.x * 128;
  const int lr = lane & 15, lk = lane >> 4;
  const int srow = lane >> 2, scol = (lane & 3) * 8;

  floatx4 acc[4][4];
#pragma unroll
  for (int i = 0; i < 4; ++i)
#pragma unroll
    for (int j = 0; j < 4; ++j) acc[i][j] = (floatx4){0.f, 0.f, 0.f, 0.f};

  for (int k0 = 0; k0 < K; k0 += 32) {
    __syncthreads();
#pragma unroll
    for (int ss = 0; ss < 2; ++ss) {
      int s = w + ss * 4;
      const u16* gA = A + (size_t)(row0 + s * 16 + srow) * K + k0 + scol;
      const u16* gB = B + (size_t)(col0 + s * 16 + srow) * K + k0 + scol;
      async16(gA, (char*)As + s * 1024);
      async16(gB, (char*)Bs + s * 1024);
    }
    __syncthreads();
    short8 a[4], b[4];
#pragma unroll
    for (int mi = 0; mi < 4; ++mi)
      a[mi] = *(const short8*)((const char*)As + (wr * 64 + mi * 16 + lr) * 64 + lk * 16);
#pragma unroll
    for (int ni = 0; ni < 4; ++ni)
      b[ni] = *(const short8*)((const char*)Bs + (wc * 64 + ni * 16 + lr) * 64 + lk * 16);
#pragma unroll
    for (int mi = 0; mi < 4; ++mi)
#pragma unroll
      for (int ni = 0; ni < 4; ++ni)
        acc[mi][ni] = __builtin_amdgcn_mfma_f32_16x16x32_bf16(a[mi], b[ni], acc[mi][ni], 0, 0, 0);
  }

#pragma unroll
  for (int mi = 0; mi < 4; ++mi)
#pragma unroll
    for (int ni = 0; ni < 4; ++ni)
#pragma unroll
      for (int r = 0; r < 4; ++r) {
        int row = row0 + wr * 64 + mi * 16 + lk * 4 + r;
        int col = col0 + wc * 64 + ni * 16 + lr;
        float v = acc[mi][ni][r];
        if (OUT_F32) ((float*)Cv)[(size_t)row * N + col] = v;
        else         ((u16*)Cv)[(size_t)row * N + col] = f2bf(v);
      }
}

// ---------------- RoPE q,k + relayout to (bh, S, 128) ----------------
__global__ void rope_qk(const u16* __restrict__ qkvb, const float2* __restrict__ cs,
                        u16* __restrict__ Qt, u16* __restrict__ Kt) {
  const int t = threadIdx.x;
  const int bh = blockIdx.y, s0 = blockIdx.x * 64;
  const int b = bh >> 4, h = bh & 15;
  const int rg = t >> 4;             // 0..15 row-in-group
  const int i4 = (t & 15) * 4;       // 0..60
#pragma unroll
  for (int pass = 0; pass < 4; ++pass) {
    const int s = s0 + pass * 16 + rg;
    float c[4], sn[4];
#pragma unroll
    for (int z = 0; z < 4; ++z) { float2 v = cs[s * 64 + i4 + z]; c[z] = v.x; sn[z] = v.y; }
#pragma unroll
    for (int m = 0; m < 2; ++m) {
      const u16* src = qkvb + (size_t)(b * S_LEN + s) * H3 + m * HDIM + h * HD;
      ushort4 x1 = *(const ushort4*)(src + i4);
      ushort4 x2 = *(const ushort4*)(src + i4 + 64);
      float a1[4] = {bf2f(x1.x), bf2f(x1.y), bf2f(x1.z), bf2f(x1.w)};
      float a2[4] = {bf2f(x2.x), bf2f(x2.y), bf2f(x2.z), bf2f(x2.w)};
      ushort4 o1, o2;
      o1.x = f2bf(a1[0] * c[0] - a2[0] * sn[0]);  o2.x = f2bf(a2[0] * c[0] + a1[0] * sn[0]);
      o1.y = f2bf(a1[1] * c[1] - a2[1] * sn[1]);  o2.y = f2bf(a2[1] * c[1] + a1[1] * sn[1]);
      o1.z = f2bf(a1[2] * c[2] - a2[2] * sn[2]);  o2.z = f2bf(a2[2] * c[2] + a1[2] * sn[2]);
      o1.w = f2bf(a1[3] * c[3] - a2[3] * sn[3]);  o2.w = f2bf(a2[3] * c[3] + a1[3] * sn[3]);
      u16* dst = (m ? Kt : Qt) + (size_t)(bh * S_LEN + s) * HD;
      *(ushort4*)(dst + i4) = o1;
      *(ushort4*)(dst + i4 + 64) = o2;
    }
  }
}

// ---------------- V transpose to (bh, 128, S) ----------------
__global__ void v_trans(const u16* __restrict__ qkvb, u16* __restrict__ Vt) {
  __shared__ u16 tile[64][132];
  const int t = threadIdx.x;
  const int bh = blockIdx.y, s0 = blockIdx.x * 64;
  const int b = bh >> 4, h = bh & 15;
#pragma unroll
  for (int it = 0; it < 8; ++it) {
    int u = it * 256 + t;
    int row = u >> 5;                 // 0..63 (s)
    int d4 = (u & 31) * 4;            // 0..124
    ushort4 vv = *(const ushort4*)(qkvb + (size_t)(b * S_LEN + s0 + row) * H3 + 2 * HDIM + h * HD + d4);
    tile[row][d4 + 0] = vv.x; tile[row][d4 + 1] = vv.y;
    tile[row][d4 + 2] = vv.z; tile[row][d4 + 3] = vv.w;
  }
  __syncthreads();
#pragma unroll
  for (int it = 0; it < 8; ++it) {
    int u = it * 256 + t;
    int d = u >> 4;                   // 0..127
    int s4 = (u & 15) * 4;            // 0..60
    ushort4 ov;
    ov.x = tile[s4 + 0][d]; ov.y = tile[s4 + 1][d];
    ov.z = tile[s4 + 2][d]; ov.w = tile[s4 + 3][d];
    *(ushort4*)(Vt + (size_t)(bh * HD + d) * S_LEN + s0 + s4) = ov;
  }
}

// ---------------- causal flash attention, balanced pairing ----------------
// grid (16, 32), 4 waves. Wave w of block x owns 16-row q-tiles t=4x+w and
// 127-t -> every wave runs exactly 65 KV iterations (perfect balance).
// 2048 waves = 2/SIMD resident, so __launch_bounds__(256,2) grants ~256
// VGPRs/wave for free -> register prefetch pipeline without scratch spills
// (round-3 lesson: without it the compiler capped at 64 VGPR and spilled
// 5.6 GB/dispatch to scratch).
__global__ __launch_bounds__(256, 2)
void attn_fwd(const u16* __restrict__ Qt, const u16* __restrict__ Kt,
              const u16* __restrict__ Vt, u16* __restrict__ Ao) {
  __shared__ __align__(16) u16 Pl[4][512];     // per-wave 16x32 P tile
  const int t = threadIdx.x, w = t >> 6, lane = t & 63;
  const int lr = lane & 15, lk = lane >> 4;
  const int bh = blockIdx.y;
  const int b = bh >> 4, h = bh & 15;
  const u16* Qb = Qt + (size_t)bh * S_LEN * HD;
  const u16* Kb = Kt + (size_t)bh * S_LEN * HD;
  const u16* Vb = Vt + (size_t)bh * HD * S_LEN;
  u16* Pw = &Pl[w][0];
  const float scale = 0.08838834764831845f;    // 1/sqrt(128)
  const int tbase = blockIdx.x * 4 + w;        // 0..63

#pragma unroll 1
  for (int half = 0; half < 2; ++half) {
    const int qt = half ? (127 - tbase) : tbase;
    const int qw0 = qt * 16;

    short8 aq[4];
#pragma unroll
    for (int c = 0; c < 4; ++c)
      aq[c] = *(const short8*)(Qb + (size_t)(qw0 + lr) * HD + c * 32 + lk * 8);

    floatx4 o[8];
#pragma unroll
    for (int i = 0; i < 8; ++i) o[i] = (floatx4){0.f, 0.f, 0.f, 0.f};
    float mrow[4] = {-1e30f, -1e30f, -1e30f, -1e30f};
    float lrow[4] = {0.f, 0.f, 0.f, 0.f};

    const int nkt = (qw0 + 47) >> 5;           // ceil((qw0+16)/32)

    short8 kc0[4], kc1[4];
#pragma unroll
    for (int c = 0; c < 4; ++c) {
      kc0[c] = *(const short8*)(Kb + (size_t)lr * HD + c * 32 + lk * 8);
      kc1[c] = *(const short8*)(Kb + (size_t)(16 + lr) * HD + c * 32 + lk * 8);
    }

    for (int kt = 0; kt < nkt; ++kt) {
      const int kv0 = kt * 32;
      const bool more = (kt + 1) < nkt;

      // V loads issued first (needed this iter: wait for them won't drain K)
      short8 vv[8];
#pragma unroll
      for (int ni = 0; ni < 8; ++ni)
        vv[ni] = *(const short8*)(Vb + (size_t)(ni * 16 + lr) * S_LEN + kv0 + lk * 8);

      // prefetch next K tile into registers (latency hidden under this iter)
      short8 kn0[4], kn1[4];
      if (more) {
#pragma unroll
        for (int c = 0; c < 4; ++c) {
          kn0[c] = *(const short8*)(Kb + (size_t)(kv0 + 32 + lr) * HD + c * 32 + lk * 8);
          kn1[c] = *(const short8*)(Kb + (size_t)(kv0 + 48 + lr) * HD + c * 32 + lk * 8);
        }
      }

      floatx4 s0 = (floatx4){0.f,0.f,0.f,0.f}, s1 = (floatx4){0.f,0.f,0.f,0.f};
      __builtin_amdgcn_s_setprio(1);
#pragma unroll
      for (int c = 0; c < 4; ++c) {
        s0 = __builtin_amdgcn_mfma_f32_16x16x32_bf16(aq[c], kc0[c], s0, 0, 0, 0);
        s1 = __builtin_amdgcn_mfma_f32_16x16x32_bf16(aq[c], kc1[c], s1, 0, 0, 0);
      }
      __builtin_amdgcn_s_setprio(0);

      const bool need_mask = (kv0 + 31) > qw0;
      float p0[4], p1[4], tmx[4];
#pragma unroll
      for (int r = 0; r < 4; ++r) {
        float v0 = s0[r] * scale, v1 = s1[r] * scale;
        if (need_mask) {
          int row = qw0 + lk * 4 + r;
          if (kv0 + lr > row)      v0 = -1e30f;
          if (kv0 + 16 + lr > row) v1 = -1e30f;
        }
        float tm = fmaxf(v0, v1);
        tm = fmaxf(tm, __shfl_xor(tm, 1));
        tm = fmaxf(tm, __shfl_xor(tm, 2));
        tm = fmaxf(tm, __shfl_xor(tm, 4));
        tm = fmaxf(tm, __shfl_xor(tm, 8));
        tmx[r] = tm; p0[r] = v0; p1[r] = v1;
      }

      bool ok = (tmx[0] <= mrow[0] + 8.f) && (tmx[1] <= mrow[1] + 8.f) &&
                (tmx[2] <= mrow[2] + 8.f) && (tmx[3] <= mrow[3] + 8.f);
      if (__all(ok)) {
        // defer-max: no rescale needed (P bounded by e^8)
#pragma unroll
        for (int r = 0; r < 4; ++r) {
          float e0 = __expf(p0[r] - mrow[r]), e1 = __expf(p1[r] - mrow[r]);
          float sum = e0 + e1;
          sum += __shfl_xor(sum, 1); sum += __shfl_xor(sum, 2);
          sum += __shfl_xor(sum, 4); sum += __shfl_xor(sum, 8);
          lrow[r] += sum;
          p0[r] = e0; p1[r] = e1;
        }
      } else {
#pragma unroll
        for (int r = 0; r < 4; ++r) {
          float mnew = fmaxf(mrow[r], tmx[r]);
          float alpha = __expf(mrow[r] - mnew);
          mrow[r] = mnew;
          float e0 = __expf(p0[r] - mnew), e1 = __expf(p1[r] - mnew);
          float sum = e0 + e1;
          sum += __shfl_xor(sum, 1); sum += __shfl_xor(sum, 2);
          sum += __shfl_xor(sum, 4); sum += __shfl_xor(sum, 8);
          lrow[r] = lrow[r] * alpha + sum;
          p0[r] = e0; p1[r] = e1;
#pragma unroll
          for (int ni = 0; ni < 8; ++ni) o[ni][r] *= alpha;
        }
      }

      // P -> LDS transpose (wave-private; compiler inserts the lgkm wait)
#pragma unroll
      for (int r = 0; r < 4; ++r) {
        Pw[(lk * 4 + r) * 32 + lr]      = f2bf(p0[r]);
        Pw[(lk * 4 + r) * 32 + 16 + lr] = f2bf(p1[r]);
      }
      short8 pa = *(const short8*)((const char*)Pw + lr * 64 + lk * 16);

      __builtin_amdgcn_s_setprio(1);
#pragma unroll
      for (int ni = 0; ni < 8; ++ni)
        o[ni] = __builtin_amdgcn_mfma_f32_16x16x32_bf16(pa, vv[ni], o[ni], 0, 0, 0);
      __builtin_amdgcn_s_setprio(0);

      if (more) {
#pragma unroll
        for (int c = 0; c < 4; ++c) { kc0[c] = kn0[c]; kc1[c] = kn1[c]; }
      }
    }

    float inv[4];
#pragma unroll
    for (int r = 0; r < 4; ++r) inv[r] = 1.0f / lrow[r];
#pragma unroll
    for (int ni = 0; ni < 8; ++ni)
#pragma unroll
      for (int r = 0; r < 4; ++r) {
        int row = qw0 + lk * 4 + r;
        Ao[(size_t)(b * S_LEN + row) * HDIM + h * HD + ni * 16 + lr] = f2bf(o[ni][r] * inv[r]);
      }
  }
}

extern "C" void kernel_launch(void* const* d_in, const int* in_sizes, int n_in,
                              void* d_out, int out_size, void* d_ws, size_t ws_size,
                              hipStream_t stream) {
  const float* x    = (const float*)d_in[0];
  // d_in[1] = attn_mask: pure causal, reconstructed analytically — never read.
  const float* Wqkv = (const float*)d_in[2];
  const float* Wout = (const float*)d_in[3];
  float* out = (float*)d_out;
  char* ws = (char*)d_ws;

  u16* xb       = (u16*)(ws + 0);              // 16.8 MB  (aliased by attn_out later)
  u16* wqkvb    = (u16*)(ws + 16777216);       // 25.2 MB
  u16* woutb    = (u16*)(ws + 41943040);       //  8.4 MB
  u16* qkvb     = (u16*)(ws + 50331648);       // 50.3 MB
  u16* Qt       = (u16*)(ws + 100663296);      // 16.8 MB
  u16* Kt       = (u16*)(ws + 117440512);      // 16.8 MB
  u16* Vt       = (u16*)(ws + 134217728);      // 16.8 MB
  float2* cs    = (float2*)(ws + 150994944);   //  1.0 MB   total ~145 MB
  u16* attn_out = xb;                          // xb dead after GEMM1

  cvt_bf16<<<8192,  256, 0, stream>>>(x,    xb,    2097152);
  cvt_bf16<<<12288, 256, 0, stream>>>(Wqkv, wqkvb, 3145728);
  cvt_bf16<<<4096,  256, 0, stream>>>(Wout, woutb, 1048576);
  rope_table<<<512, 256, 0, stream>>>(cs);

  gemm_bt<0><<<dim3(48, 32), 256, 0, stream>>>(xb, wqkvb, qkvb, 4096, H3, HDIM);

  rope_qk<<<dim3(32, 32), 256, 0, stream>>>(qkvb, cs, Qt, Kt);
  v_trans<<<dim3(32, 32), 256, 0, stream>>>(qkvb, Vt);

  attn_fwd<<<dim3(16, 32), 256, 0, stream>>>(Qt, Kt, Vt, attn_out);

  gemm_bt<1><<<dim3(16, 32), 256, 0, stream>>>(attn_out, woutb, out, 4096, HDIM, HDIM);
}